// Round 4
// baseline (178.562 us; speedup 1.0000x reference)
//
#include <hip/hip_runtime.h>

#define N_ATOMS 2048
#define NSPEC 7
#define NR 16
#define NFEAT 112          // 7 species * 16 radial shifts; aev[112:1008] is zero padding
#define RCR_F 5.2f
#define H0 256
#define H1 192
#define H2 160
#define W0_PITCH 1008      // W0 rows are 1008 wide; only first 112 columns matter
#define TILE 8             // atoms per fused block
#define NTILES (N_ATOMS / TILE)

// ---- workspace layout (byte offsets into d_ws) ----
#define WS_SEG     0         // int[8] species segment starts (seg[7] = N)
#define WS_SCOORD  16384     // float4[2048] species-sorted coordinates

__device__ __forceinline__ float celu01(float x) {
    return x > 0.f ? x : 0.1f * (__expf(x * 10.f) - 1.f);
}

// ---------------- K0: counting sort by species + init ----------------
__global__ __launch_bounds__(256) void sort_kernel(const int* __restrict__ species,
                                                   const float* __restrict__ coords,
                                                   int* __restrict__ seg,
                                                   float4* __restrict__ scoord,
                                                   float* __restrict__ out) {
    __shared__ int cnt[NSPEC];
    __shared__ int cur[NSPEC];
    int t = threadIdx.x;
    if (t < NSPEC) cnt[t] = 0;
    __syncthreads();
    for (int a = t; a < N_ATOMS; a += 256) atomicAdd(&cnt[species[a]], 1);
    __syncthreads();
    if (t == 0) {
        int run = 0;
        for (int s = 0; s < NSPEC; s++) { seg[s] = run; cur[s] = run; run += cnt[s]; }
        seg[NSPEC] = run;
        out[0] = 0.0f;   // d_out is poisoned before every call
    }
    __syncthreads();
    for (int a = t; a < N_ATOMS; a += 256) {
        int sp = species[a];
        int pos = atomicAdd(&cur[sp], 1);
        scoord[pos] = make_float4(coords[3*a], coords[3*a+1], coords[3*a+2], 0.f);
    }
}

// ---------------- K1: fused AEV + 4-layer MLP + energy reduce ----------------
// Grid (NTILES, NSPEC); block = 512 threads = 8 waves, handles TILE=8 sorted
// atoms of species blockIdx.y starting at seg[s] + blockIdx.x*8.
// Phase A: wave w computes atom (base+w)'s 112-dim radial AEV into LDS.
// Phases B/C/D: dense layers with thread t = (o<<1)|ks; K split 2 ways,
// shfl_xor(1) reduce. Activations stay in LDS end-to-end; same-address LDS
// broadcast across the o-lanes is conflict-free. All loop bounds are
// compile-time so accumulators stay in VGPRs (round-2 scratch-spill lesson).
__global__ __launch_bounds__(512) void fused_kernel(const float4* __restrict__ scoord,
                                                    const int* __restrict__ seg,
                                                    const float* __restrict__ ShfR,
                                                    const float* __restrict__ EtaR,
                                                    const float* __restrict__ W0,
                                                    const float* __restrict__ b0,
                                                    const float* __restrict__ W1,
                                                    const float* __restrict__ b1,
                                                    const float* __restrict__ W2,
                                                    const float* __restrict__ b2,
                                                    const float* __restrict__ Wf,
                                                    const float* __restrict__ bf,
                                                    float* __restrict__ out) {
    __shared__ float aevs[TILE][NFEAT];   // 3.5 KB
    __shared__ float h0s[TILE][H0];       // 8 KB
    __shared__ float h1s[TILE][H1];       // 6 KB
    __shared__ float bsum;

    int s = blockIdx.y;
    int segend = seg[s + 1];
    int base = seg[s] + blockIdx.x * TILE;
    if (base >= segend) return;           // block-uniform exit
    int n_act = min(TILE, segend - base);

    int t = threadIdx.x;
    if (t == 0) bsum = 0.f;

    // ---------- Phase A: AEV, one wave per atom ----------
    {
        int w = t >> 6, lane = t & 63;
        int p = base + (w < n_act ? w : 0);        // duplicate atom for pad waves (finite junk)
        int sA = lane >> 3, c = lane & 7;          // species group / chunk within group
        float4 ci = scoord[p];
        float eta = EtaR[0];
        float shf[NR];
#pragma unroll
        for (int r = 0; r < NR; r++) shf[r] = ShfR[r];   // uniform -> SGPRs
        float acc[NR];
#pragma unroll
        for (int r = 0; r < NR; r++) acc[r] = 0.f;

        int kbeg = 0, kend = 0;
        if (sA < NSPEC) { kbeg = seg[sA] + c; kend = seg[sA + 1]; }
        const float rc2 = RCR_F * RCR_F;
        const float cosk = 3.14159265358979f / RCR_F;

        for (int k = kbeg; k < kend; k += 8) {
            float4 cj = scoord[k];
            float dx = ci.x - cj.x, dy = ci.y - cj.y, dz = ci.z - cj.z;
            float dsq = dx*dx + dy*dy + dz*dz;
            bool valid = (dsq > 0.f) && (dsq <= rc2);   // excludes self
            float d = sqrtf(dsq);
            float fc = 0.5f * __cosf(d * cosk) + 0.5f;
            fc = valid ? fc : 0.f;
#pragma unroll
            for (int r = 0; r < NR; r++) {
                float u = d - shf[r];
                acc[r] = fmaf(__expf(-eta * u * u), fc, acc[r]);  // underflow -> 0, matches ref
            }
        }
#pragma unroll
        for (int r = 0; r < NR; r++) {
            float v = acc[r];
            v += __shfl_xor(v, 1);
            v += __shfl_xor(v, 2);
            v += __shfl_xor(v, 4);
            acc[r] = v;
        }
        if (sA < NSPEC && c == 0) {
            float* dst = &aevs[w][sA * NR];
#pragma unroll
            for (int r = 0; r < NR; r += 4)
                *(float4*)(dst + r) = make_float4(acc[r], acc[r+1], acc[r+2], acc[r+3]);
        }
    }
    __syncthreads();

    int o = t >> 1, ks = t & 1;

    // ---------- Phase B: layer0  aev[112] -> h0[256] ----------
    {
        const float* Wr = W0 + (size_t)(s * H0 + o) * W0_PITCH + ks * 4;
        float bias = b0[s * H0 + o];
        float acc[TILE];
#pragma unroll
        for (int q = 0; q < TILE; q++) acc[q] = 0.f;
#pragma unroll 7
        for (int i = 0; i < NFEAT / 8; i++) {      // 14 iters, 8 floats per i
            float4 w = *(const float4*)(Wr + i * 8);
#pragma unroll
            for (int q = 0; q < TILE; q++) {
                float4 a = *(const float4*)(&aevs[q][i * 8 + ks * 4]);
                acc[q] += w.x*a.x + w.y*a.y + w.z*a.z + w.w*a.w;
            }
        }
#pragma unroll
        for (int q = 0; q < TILE; q++) {
            float v = acc[q];
            v += __shfl_xor(v, 1);
            if (ks == 0) h0s[q][o] = celu01(v + bias);
        }
    }
    __syncthreads();

    // ---------- Phase C: layer1  h0[256] -> h1[192] ----------
    if (o < H1) {
        const float* Wr = W1 + (size_t)(s * H1 + o) * H0 + ks * 4;
        float bias = b1[s * H1 + o];
        float acc[TILE];
#pragma unroll
        for (int q = 0; q < TILE; q++) acc[q] = 0.f;
#pragma unroll 4
        for (int i = 0; i < H0 / 8; i++) {         // 32 iters
            float4 w = *(const float4*)(Wr + i * 8);
#pragma unroll
            for (int q = 0; q < TILE; q++) {
                float4 a = *(const float4*)(&h0s[q][i * 8 + ks * 4]);
                acc[q] += w.x*a.x + w.y*a.y + w.z*a.z + w.w*a.w;
            }
        }
#pragma unroll
        for (int q = 0; q < TILE; q++) {
            float v = acc[q];
            v += __shfl_xor(v, 1);
            if (ks == 0) h1s[q][o] = celu01(v + bias);
        }
    }
    __syncthreads();

    // ---------- Phase D: layer2 + final dot ----------
    float contrib = 0.f;
    if (o < H2) {
        const float* Wr = W2 + (size_t)(s * H2 + o) * H1 + ks * 4;
        float bias = b2[s * H2 + o];
        float wf = Wf[s * H2 + o];
        float acc[TILE];
#pragma unroll
        for (int q = 0; q < TILE; q++) acc[q] = 0.f;
#pragma unroll 4
        for (int i = 0; i < H1 / 8; i++) {         // 24 iters
            float4 w = *(const float4*)(Wr + i * 8);
#pragma unroll
            for (int q = 0; q < TILE; q++) {
                float4 a = *(const float4*)(&h1s[q][i * 8 + ks * 4]);
                acc[q] += w.x*a.x + w.y*a.y + w.z*a.z + w.w*a.w;
            }
        }
#pragma unroll
        for (int q = 0; q < TILE; q++) {
            float v = acc[q];
            v += __shfl_xor(v, 1);
            if (ks == 0 && q < n_act) contrib += wf * celu01(v + bias);
        }
    }
    if (t == 0) contrib += (float)n_act * bf[s];   // final-layer bias, once per atom

    // block reduction over 8 waves
    float v = contrib;
    v += __shfl_down(v, 32);
    v += __shfl_down(v, 16);
    v += __shfl_down(v, 8);
    v += __shfl_down(v, 4);
    v += __shfl_down(v, 2);
    v += __shfl_down(v, 1);
    if ((t & 63) == 0) atomicAdd(&bsum, v);
    __syncthreads();
    if (t == 0) atomicAdd(out, bsum);
}

extern "C" void kernel_launch(void* const* d_in, const int* in_sizes, int n_in,
                              void* d_out, int out_size, void* d_ws, size_t ws_size,
                              hipStream_t stream) {
    const int*   species = (const int*)d_in[0];
    const float* coords  = (const float*)d_in[1];
    const float* EtaR    = (const float*)d_in[2];
    const float* ShfR    = (const float*)d_in[3];
    const float* W0      = (const float*)d_in[4];
    const float* b0      = (const float*)d_in[5];
    const float* W1      = (const float*)d_in[6];
    const float* b1      = (const float*)d_in[7];
    const float* W2      = (const float*)d_in[8];
    const float* b2      = (const float*)d_in[9];
    const float* Wf      = (const float*)d_in[10];
    const float* bf      = (const float*)d_in[11];
    float* out = (float*)d_out;
    char* ws = (char*)d_ws;

    int*    seg    = (int*)(ws + WS_SEG);
    float4* scoord = (float4*)(ws + WS_SCOORD);

    hipLaunchKernelGGL(sort_kernel, dim3(1), dim3(256), 0, stream,
                       species, coords, seg, scoord, out);
    hipLaunchKernelGGL(fused_kernel, dim3(NTILES, NSPEC), dim3(512), 0, stream,
                       scoord, seg, ShfR, EtaR, W0, b0, W1, b1, W2, b2, Wf, bf, out);
}

// Round 5
// 154.734 us; speedup vs baseline: 1.1540x; 1.1540x over previous
//
#include <hip/hip_runtime.h>

#define N_ATOMS 2048
#define NSPEC 7
#define NR 16
#define NFEAT 112          // 7 species * 16 radial shifts; aev[112:1008] is zero padding
#define RCR_F 5.2f
#define H0 256
#define H1 192
#define H2 160
#define W0_PITCH 1008      // W0 rows are 1008 wide; only first 112 columns matter
#define TILE 8             // atoms per MLP block
#define NTILES (N_ATOMS / TILE)

// ---- workspace layout (byte offsets into d_ws) ----
#define WS_SEG     0         // int[8] species segment starts (seg[7] = N)
#define WS_SCOORD  16384     // float4[2048] species-sorted coordinates
#define WS_AEV     65536     // float[2048*112] AEV per sorted atom

__device__ __forceinline__ float celu01(float x) {
    return x > 0.f ? x : 0.1f * (__expf(x * 10.f) - 1.f);
}

// ---------------- K0: counting sort by species + init ----------------
__global__ __launch_bounds__(256) void sort_kernel(const int* __restrict__ species,
                                                   const float* __restrict__ coords,
                                                   int* __restrict__ seg,
                                                   float4* __restrict__ scoord,
                                                   float* __restrict__ out) {
    __shared__ int cnt[NSPEC];
    __shared__ int cur[NSPEC];
    int t = threadIdx.x;
    if (t < NSPEC) cnt[t] = 0;
    __syncthreads();
    for (int a = t; a < N_ATOMS; a += 256) atomicAdd(&cnt[species[a]], 1);
    __syncthreads();
    if (t == 0) {
        int run = 0;
        for (int s = 0; s < NSPEC; s++) { seg[s] = run; cur[s] = run; run += cnt[s]; }
        seg[NSPEC] = run;
        out[0] = 0.0f;   // d_out is poisoned before every call
    }
    __syncthreads();
    for (int a = t; a < N_ATOMS; a += 256) {
        int sp = species[a];
        int pos = atomicAdd(&cur[sp], 1);
        scoord[pos] = make_float4(coords[3*a], coords[3*a+1], coords[3*a+2], 0.f);
    }
}

// ---------------- K1: pair-parallel radial AEV ----------------
// Grid (N_ATOMS/4, NSPEC), block 256 = 4 waves. Wave w computes the 16 AEV
// entries of (atom p = bx*4+w, neighbor-species s = by): all 64 lanes walk
// segment s lane-strided (coalesced float4 loads), 16 independent exps per
// pair per lane, then 6-round shfl_xor butterfly over the 16 accumulators.
// 14336 waves -> full occupancy; every lane active; valid for any p.
__global__ __launch_bounds__(256) void aev_kernel(const float4* __restrict__ scoord,
                                                  const int* __restrict__ seg,
                                                  const float* __restrict__ ShfR,
                                                  const float* __restrict__ EtaR,
                                                  float* __restrict__ aev) {
    int s = blockIdx.y;
    int p = blockIdx.x * 4 + (threadIdx.x >> 6);
    int lane = threadIdx.x & 63;

    float4 ci = scoord[p];
    float eta = EtaR[0];
    float shf[NR];
#pragma unroll
    for (int r = 0; r < NR; r++) shf[r] = ShfR[r];   // uniform -> SGPRs
    float acc[NR];
#pragma unroll
    for (int r = 0; r < NR; r++) acc[r] = 0.f;

    int kbeg = seg[s] + lane;
    int kend = seg[s + 1];
    const float rc2 = RCR_F * RCR_F;
    const float cosk = 3.14159265358979f / RCR_F;

    for (int k = kbeg; k < kend; k += 64) {
        float4 cj = scoord[k];
        float dx = ci.x - cj.x, dy = ci.y - cj.y, dz = ci.z - cj.z;
        float dsq = dx*dx + dy*dy + dz*dz;
        bool valid = (dsq > 0.f) && (dsq <= rc2);   // excludes self (d==0)
        float d = sqrtf(dsq);
        float fc = 0.5f * __cosf(d * cosk) + 0.5f;
        fc = valid ? fc : 0.f;
#pragma unroll
        for (int r = 0; r < NR; r++) {
            float u = d - shf[r];
            acc[r] = fmaf(__expf(-eta * u * u), fc, acc[r]);  // underflow -> 0, matches ref
        }
    }
    // full-wave butterfly (lanes past segment end carry acc=0)
#pragma unroll
    for (int r = 0; r < NR; r++) {
        float v = acc[r];
        v += __shfl_xor(v, 1);
        v += __shfl_xor(v, 2);
        v += __shfl_xor(v, 4);
        v += __shfl_xor(v, 8);
        v += __shfl_xor(v, 16);
        v += __shfl_xor(v, 32);
        acc[r] = v;
    }
    if (lane == 0) {
        float* dst = aev + (size_t)p * NFEAT + s * NR;
#pragma unroll
        for (int r = 0; r < NR; r += 4)
            *(float4*)(dst + r) = make_float4(acc[r], acc[r+1], acc[r+2], acc[r+3]);
    }
}

// ---------------- K2: fused 4-layer MLP + energy reduce ----------------
// Grid (NTILES, NSPEC); block 512 handles TILE=8 sorted atoms of species
// blockIdx.y. AEV slab staged global->LDS (coalesced, contiguous), layers
// flow LDS->LDS. Thread t = (o<<1)|ks; shfl_xor(1) K-reduce. All loop
// bounds compile-time so accumulators stay in VGPRs (R2 scratch lesson).
__global__ __launch_bounds__(512) void mlp_kernel(const float* __restrict__ aev,
                                                  const int* __restrict__ seg,
                                                  const float* __restrict__ W0,
                                                  const float* __restrict__ b0,
                                                  const float* __restrict__ W1,
                                                  const float* __restrict__ b1,
                                                  const float* __restrict__ W2,
                                                  const float* __restrict__ b2,
                                                  const float* __restrict__ Wf,
                                                  const float* __restrict__ bf,
                                                  float* __restrict__ out) {
    __shared__ float aevs[TILE][NFEAT];   // 3.5 KB
    __shared__ float h0s[TILE][H0];       // 8 KB
    __shared__ float h1s[TILE][H1];       // 6 KB
    __shared__ float bsum;

    int s = blockIdx.y;
    int segend = seg[s + 1];
    int base = seg[s] + blockIdx.x * TILE;
    if (base >= segend) return;           // block-uniform exit
    int n_act = min(TILE, segend - base);

    int t = threadIdx.x;
    if (t == 0) bsum = 0.f;

    {   // stage: contiguous slab aev[base*112 .. +8*112), zero-pad tail atoms
        float4* dst = (float4*)&aevs[0][0];
        const float4* src = (const float4*)(aev + (size_t)base * NFEAT);
        int nfl4 = min(TILE * (NFEAT / 4), (N_ATOMS - base) * (NFEAT / 4));
        for (int j = t; j < TILE * (NFEAT / 4); j += 512)
            dst[j] = (j < nfl4) ? src[j] : make_float4(0.f, 0.f, 0.f, 0.f);
    }
    __syncthreads();

    int o = t >> 1, ks = t & 1;

    // ---------- layer0: aev[112] -> h0[256] ----------
    {
        const float* Wr = W0 + (size_t)(s * H0 + o) * W0_PITCH + ks * 4;
        float bias = b0[s * H0 + o];
        float acc[TILE];
#pragma unroll
        for (int q = 0; q < TILE; q++) acc[q] = 0.f;
#pragma unroll 7
        for (int i = 0; i < NFEAT / 8; i++) {      // 14 iters, 8 floats per i
            float4 w = *(const float4*)(Wr + i * 8);
#pragma unroll
            for (int q = 0; q < TILE; q++) {
                float4 a = *(const float4*)(&aevs[q][i * 8 + ks * 4]);
                acc[q] += w.x*a.x + w.y*a.y + w.z*a.z + w.w*a.w;
            }
        }
#pragma unroll
        for (int q = 0; q < TILE; q++) {
            float v = acc[q];
            v += __shfl_xor(v, 1);
            if (ks == 0) h0s[q][o] = celu01(v + bias);
        }
    }
    __syncthreads();

    // ---------- layer1: h0[256] -> h1[192] ----------
    if (o < H1) {
        const float* Wr = W1 + (size_t)(s * H1 + o) * H0 + ks * 4;
        float bias = b1[s * H1 + o];
        float acc[TILE];
#pragma unroll
        for (int q = 0; q < TILE; q++) acc[q] = 0.f;
#pragma unroll 4
        for (int i = 0; i < H0 / 8; i++) {         // 32 iters
            float4 w = *(const float4*)(Wr + i * 8);
#pragma unroll
            for (int q = 0; q < TILE; q++) {
                float4 a = *(const float4*)(&h0s[q][i * 8 + ks * 4]);
                acc[q] += w.x*a.x + w.y*a.y + w.z*a.z + w.w*a.w;
            }
        }
#pragma unroll
        for (int q = 0; q < TILE; q++) {
            float v = acc[q];
            v += __shfl_xor(v, 1);
            if (ks == 0) h1s[q][o] = celu01(v + bias);
        }
    }
    __syncthreads();

    // ---------- layer2 + final dot ----------
    float contrib = 0.f;
    if (o < H2) {
        const float* Wr = W2 + (size_t)(s * H2 + o) * H1 + ks * 4;
        float bias = b2[s * H2 + o];
        float wf = Wf[s * H2 + o];
        float acc[TILE];
#pragma unroll
        for (int q = 0; q < TILE; q++) acc[q] = 0.f;
#pragma unroll 4
        for (int i = 0; i < H1 / 8; i++) {         // 24 iters
            float4 w = *(const float4*)(Wr + i * 8);
#pragma unroll
            for (int q = 0; q < TILE; q++) {
                float4 a = *(const float4*)(&h1s[q][i * 8 + ks * 4]);
                acc[q] += w.x*a.x + w.y*a.y + w.z*a.z + w.w*a.w;
            }
        }
#pragma unroll
        for (int q = 0; q < TILE; q++) {
            float v = acc[q];
            v += __shfl_xor(v, 1);
            if (ks == 0 && q < n_act) contrib += wf * celu01(v + bias);
        }
    }
    if (t == 0) contrib += (float)n_act * bf[s];   // final-layer bias, once per atom

    float v = contrib;
    v += __shfl_down(v, 32);
    v += __shfl_down(v, 16);
    v += __shfl_down(v, 8);
    v += __shfl_down(v, 4);
    v += __shfl_down(v, 2);
    v += __shfl_down(v, 1);
    if ((t & 63) == 0) atomicAdd(&bsum, v);
    __syncthreads();
    if (t == 0) atomicAdd(out, bsum);
}

extern "C" void kernel_launch(void* const* d_in, const int* in_sizes, int n_in,
                              void* d_out, int out_size, void* d_ws, size_t ws_size,
                              hipStream_t stream) {
    const int*   species = (const int*)d_in[0];
    const float* coords  = (const float*)d_in[1];
    const float* EtaR    = (const float*)d_in[2];
    const float* ShfR    = (const float*)d_in[3];
    const float* W0      = (const float*)d_in[4];
    const float* b0      = (const float*)d_in[5];
    const float* W1      = (const float*)d_in[6];
    const float* b1      = (const float*)d_in[7];
    const float* W2      = (const float*)d_in[8];
    const float* b2      = (const float*)d_in[9];
    const float* Wf      = (const float*)d_in[10];
    const float* bf      = (const float*)d_in[11];
    float* out = (float*)d_out;
    char* ws = (char*)d_ws;

    int*    seg    = (int*)(ws + WS_SEG);
    float4* scoord = (float4*)(ws + WS_SCOORD);
    float*  aev    = (float*)(ws + WS_AEV);

    hipLaunchKernelGGL(sort_kernel, dim3(1), dim3(256), 0, stream,
                       species, coords, seg, scoord, out);
    hipLaunchKernelGGL(aev_kernel, dim3(N_ATOMS / 4, NSPEC), dim3(256), 0, stream,
                       scoord, seg, ShfR, EtaR, aev);
    hipLaunchKernelGGL(mlp_kernel, dim3(NTILES, NSPEC), dim3(512), 0, stream,
                       aev, seg, W0, b0, W1, b1, W2, b2, Wf, bf, out);
}